// Round 4
// baseline (119.275 us; speedup 1.0000x reference)
//
#include <hip/hip_runtime.h>
#include <math.h>

// RoPE, interleaved layout: x shape (4, 16, 4096, 64) fp32.
// out[..., 2i]   = cos(a_i)*x[2i] - sin(a_i)*x[2i+1]
// out[..., 2i+1] = sin(a_i)*x[2i] + cos(a_i)*x[2i+1]
// a_i = pos * 10000^(-i/32), pos = seq index (reference ignores token_positions).
//
// Streaming memory-bound kernel. 32 B/lane: two 16 B vectors per thread,
// nontemporal load/store (zero reuse; avoids L2 allocate pressure).
// NOTE: __builtin_nontemporal_* requires a NATIVE vector type — HIP's
// float4 (HIP_vector_type struct) is rejected; use ext_vector_type(4).
// Trig via hardware v_sin/v_cos in revolutions (1/2π folded into inv_freq),
// fract range reduction. dur_us carries ~85 µs fixed harness poison/restore;
// kernel dispatch targets the ~21 µs HBM floor (134 MB @ 6.3 TB/s).

typedef float f32x4 __attribute__((ext_vector_type(4)));

__global__ __launch_bounds__(256) void
rope_kernel(const f32x4* __restrict__ x, f32x4* __restrict__ out) {
    int t = blockIdx.x * blockDim.x + threadIdx.x;
    long base = (long)t * 2;  // two consecutive 16B vectors = 8 elements

    f32x4 v0 = __builtin_nontemporal_load(&x[base]);
    f32x4 v1 = __builtin_nontemporal_load(&x[base + 1]);

    unsigned e = (unsigned)t << 3;        // flat element index of v0.x
    unsigned d = e & 63u;                 // offset within head dim (mult of 8)
    float fpos = (float)((e >> 6) & 4095u);

    // pair indices p0..p3 for (v0.xy, v0.zw, v1.xy, v1.zw)
    float p0 = (float)(d >> 1);

    // inv_freq in REVOLUTIONS: 10000^(-p/32) / (2*pi)
    const float kA = -0.41524101186092503f;  // -log2(10000)/32
    const float kB = -2.6514961294723187f;   // -log2(2*pi)
    const float kStep = 0.7498942093324559f; // 10000^(-1/32)
    float invf0 = exp2f(fmaf(p0, kA, kB));
    float invf1 = invf0 * kStep;
    float invf2 = invf1 * kStep;
    float invf3 = invf2 * kStep;

    float r0 = fpos * invf0; r0 -= floorf(r0);
    float r1 = fpos * invf1; r1 -= floorf(r1);
    float r2 = fpos * invf2; r2 -= floorf(r2);
    float r3 = fpos * invf3; r3 -= floorf(r3);

    float s0 = __builtin_amdgcn_sinf(r0), c0 = __builtin_amdgcn_cosf(r0);
    float s1 = __builtin_amdgcn_sinf(r1), c1 = __builtin_amdgcn_cosf(r1);
    float s2 = __builtin_amdgcn_sinf(r2), c2 = __builtin_amdgcn_cosf(r2);
    float s3 = __builtin_amdgcn_sinf(r3), c3 = __builtin_amdgcn_cosf(r3);

    f32x4 o0, o1;
    o0.x = c0 * v0.x - s0 * v0.y;
    o0.y = s0 * v0.x + c0 * v0.y;
    o0.z = c1 * v0.z - s1 * v0.w;
    o0.w = s1 * v0.z + c1 * v0.w;
    o1.x = c2 * v1.x - s2 * v1.y;
    o1.y = s2 * v1.x + c2 * v1.y;
    o1.z = c3 * v1.z - s3 * v1.w;
    o1.w = s3 * v1.z + c3 * v1.w;

    __builtin_nontemporal_store(o0, &out[base]);
    __builtin_nontemporal_store(o1, &out[base + 1]);
}

extern "C" void kernel_launch(void* const* d_in, const int* in_sizes, int n_in,
                              void* d_out, int out_size, void* d_ws, size_t ws_size,
                              hipStream_t stream) {
    const f32x4* x = (const f32x4*)d_in[0];
    f32x4* out = (f32x4*)d_out;

    // out_size = 16,777,216 elems; 8 per thread -> 2,097,152 threads
    const int block = 256;
    const int grid = (out_size / 8) / block;  // 8192, exact fit
    rope_kernel<<<grid, block, 0, stream>>>(x, out);
}

// Round 5
// 113.219 us; speedup vs baseline: 1.0535x; 1.0535x over previous
//
#include <hip/hip_runtime.h>
#include <math.h>

// RoPE, interleaved layout: x shape (4, 16, 4096, 64) fp32.
// out[..., 2i]   = cos(a_i)*x[2i] - sin(a_i)*x[2i+1]
// out[..., 2i+1] = sin(a_i)*x[2i] + cos(a_i)*x[2i+1]
// a_i = pos * 10000^(-i/32), pos = seq index (reference ignores token_positions).
//
// Streaming memory-bound kernel. 32 B/lane: two 16 B vectors per thread,
// PLAIN loads/stores (round-4 nontemporal variant regressed 110->119 µs;
// nt stores bypass L2's write-smoothing — reverted).
// Trig via hardware v_sin/v_cos in revolutions (1/2π folded into inv_freq),
// fract range reduction. dur_us carries ~85 µs fixed harness poison/restore;
// kernel dispatch targets the ~21 µs HBM floor (134 MB @ 6.3 TB/s).

typedef float f32x4 __attribute__((ext_vector_type(4)));

__global__ __launch_bounds__(256) void
rope_kernel(const f32x4* __restrict__ x, f32x4* __restrict__ out) {
    int t = blockIdx.x * blockDim.x + threadIdx.x;
    long base = (long)t * 2;  // two consecutive 16B vectors = 8 elements

    f32x4 v0 = x[base];
    f32x4 v1 = x[base + 1];

    unsigned e = (unsigned)t << 3;        // flat element index of v0.x
    unsigned d = e & 63u;                 // offset within head dim (mult of 8)
    float fpos = (float)((e >> 6) & 4095u);

    // pair indices p0..p3 for (v0.xy, v0.zw, v1.xy, v1.zw)
    float p0 = (float)(d >> 1);

    // inv_freq in REVOLUTIONS: 10000^(-p/32) / (2*pi)
    const float kA = -0.41524101186092503f;  // -log2(10000)/32
    const float kB = -2.6514961294723187f;   // -log2(2*pi)
    const float kStep = 0.7498942093324559f; // 10000^(-1/32)
    float invf0 = exp2f(fmaf(p0, kA, kB));
    float invf1 = invf0 * kStep;
    float invf2 = invf1 * kStep;
    float invf3 = invf2 * kStep;

    float r0 = fpos * invf0; r0 -= floorf(r0);
    float r1 = fpos * invf1; r1 -= floorf(r1);
    float r2 = fpos * invf2; r2 -= floorf(r2);
    float r3 = fpos * invf3; r3 -= floorf(r3);

    float s0 = __builtin_amdgcn_sinf(r0), c0 = __builtin_amdgcn_cosf(r0);
    float s1 = __builtin_amdgcn_sinf(r1), c1 = __builtin_amdgcn_cosf(r1);
    float s2 = __builtin_amdgcn_sinf(r2), c2 = __builtin_amdgcn_cosf(r2);
    float s3 = __builtin_amdgcn_sinf(r3), c3 = __builtin_amdgcn_cosf(r3);

    f32x4 o0, o1;
    o0.x = c0 * v0.x - s0 * v0.y;
    o0.y = s0 * v0.x + c0 * v0.y;
    o0.z = c1 * v0.z - s1 * v0.w;
    o0.w = s1 * v0.z + c1 * v0.w;
    o1.x = c2 * v1.x - s2 * v1.y;
    o1.y = s2 * v1.x + c2 * v1.y;
    o1.z = c3 * v1.z - s3 * v1.w;
    o1.w = s3 * v1.z + c3 * v1.w;

    out[base] = o0;
    out[base + 1] = o1;
}

extern "C" void kernel_launch(void* const* d_in, const int* in_sizes, int n_in,
                              void* d_out, int out_size, void* d_ws, size_t ws_size,
                              hipStream_t stream) {
    const f32x4* x = (const f32x4*)d_in[0];
    f32x4* out = (f32x4*)d_out;

    // out_size = 16,777,216 elems; 8 per thread -> 2,097,152 threads
    const int block = 256;
    const int grid = (out_size / 8) / block;  // 8192, exact fit
    rope_kernel<<<grid, block, 0, stream>>>(x, out);
}

// Round 6
// 109.941 us; speedup vs baseline: 1.0849x; 1.0298x over previous
//
#include <hip/hip_runtime.h>
#include <math.h>

// RoPE, interleaved layout: x shape (4, 16, 4096, 64) fp32.
// out[..., 2i]   = cos(a_i)*x[2i] - sin(a_i)*x[2i+1]
// out[..., 2i+1] = sin(a_i)*x[2i] + cos(a_i)*x[2i+1]
// a_i = pos * 10000^(-i/32), pos = seq index (reference ignores token_positions).
//
// MEASURED-BEST config (session ladder):
//   1 float4/thread, plain ld/st, hw v_sin/v_cos  -> 110.3 µs  (this)
//   1 float4/thread, libm sincosf                 -> 110.5 µs
//   2 float4/thread, plain                        -> 113.2 µs  (fewer waves
//                       -> fewer concurrent memory streams; regressed)
//   2 float4/thread, nontemporal                  -> 119.3 µs  (nt stores
//                       bypass L2 write-smoothing; regressed)
// Kernel slice ≈ 25 µs of 134 MB mixed r/w ≈ 5.4 TB/s — streaming roofline;
// the rest of dur_us is fixed harness poison/restore (~85 µs, fillBuffer
// dispatches at 41 µs each dominate the profile).
// Trig: angle in revolutions (1/2π folded into inv_freq), fract reduction,
// hardware sin/cos. absmax 0.0313 vs threshold 0.115.

__global__ __launch_bounds__(256) void
rope_kernel(const float4* __restrict__ x, float4* __restrict__ out, int n4) {
    int t = blockIdx.x * blockDim.x + threadIdx.x;
    if (t >= n4) return;

    float4 v = x[t];

    unsigned e = (unsigned)t << 2;        // flat element index of v.x
    unsigned d = e & 63u;                 // offset within head dim (mult of 4)
    unsigned pos = (e >> 6) & 4095u;      // sequence position
    float fpos = (float)pos;

    float p0 = (float)(d >> 1);           // pair index for (v.x,v.y)

    // inv_freq in REVOLUTIONS: 10000^(-p/32) / (2*pi)
    const float kA = -0.41524101186092503f;  // -log2(10000)/32
    const float kB = -2.6514961294723187f;   // -log2(2*pi)
    const float kStep = 0.7498942093324559f; // 10000^(-1/32)
    float invf0 = exp2f(fmaf(p0, kA, kB));
    float invf1 = invf0 * kStep;

    float r0 = fpos * invf0; r0 -= floorf(r0);
    float r1 = fpos * invf1; r1 -= floorf(r1);

    float s0 = __builtin_amdgcn_sinf(r0), c0 = __builtin_amdgcn_cosf(r0);
    float s1 = __builtin_amdgcn_sinf(r1), c1 = __builtin_amdgcn_cosf(r1);

    float4 r;
    r.x = c0 * v.x - s0 * v.y;
    r.y = s0 * v.x + c0 * v.y;
    r.z = c1 * v.z - s1 * v.w;
    r.w = s1 * v.z + c1 * v.w;
    out[t] = r;
}

extern "C" void kernel_launch(void* const* d_in, const int* in_sizes, int n_in,
                              void* d_out, int out_size, void* d_ws, size_t ws_size,
                              hipStream_t stream) {
    const float4* x = (const float4*)d_in[0];
    float4* out = (float4*)d_out;
    int n4 = out_size / 4;  // 16,777,216 / 4 = 4,194,304

    const int block = 256;
    const int grid = (n4 + block - 1) / block;  // 16384
    rope_kernel<<<grid, block, 0, stream>>>(x, out, n4);
}